// Round 14
// baseline (138.235 us; speedup 1.0000x reference)
//
#include <hip/hip_runtime.h>

// Chamfer distance — exact, pruned. Serial adaptive scans (R15-R17) all
// pinned at ~48us: per-tile dependent chain (reduce->bm->gap->stage) x
// up-to-32 tiles on edge-slab blocks = single serial tail. R18 removes
// the dependency: (1) bound pass computes per-slab exact-conservative
// window from per-pred NN upper bounds (128 x-neighbors); (2) chunk pass
// is embarrassingly parallel: block=(slab,chunk), fixed 512-target chunks,
// R16 conflict-free tile compute, per-pred combine via uint atomicMin
// (positive floats: bit order = value order; monotone rounding keeps the
// min selection exact). Worst slab = 16 PARALLEL blocks, not 32 serial
// tiles. Predict: chunk 8-15us, bench 40-55us, absmax 0.
//
// Carried findings: pk_fma = 2x scalar (no packed fp32 gain); launch_
// bounds arg2 = min BLOCKS/CU, VGPR cap = 2048/(arg2 x waves_per_block);
// brute floor 46.3us.

#define NBINS 256
#define XLO -6.0f
#define XHI 6.0f

#define SLABP 64    // preds per slab
#define CHUNK 512   // targets per chunk
#define MAXCH 16    // max chunks per slab = M/CHUNK
#define UBN 64      // ub scan: +-UBN positions around pred's bin start

// bin sort
#define BST 1024

// brute-force fallback params (R11, unchanged)
#define THREADS 512
#define P 8
#define G 128
#define TILE 32
#define LSTRIDE (TILE + 1)
#define TSPLIT 2
#define BUFSZ (32 * LSTRIDE)

typedef float float2_t __attribute__((ext_vector_type(2)));
typedef float float4_t __attribute__((ext_vector_type(4)));

// ---------- pass 1: counting sort by x-bin, emit float4 {x,y,z,|q|^2} ----
__global__ __launch_bounds__(BST) void bin_sort_kernel(
    const float* __restrict__ pred, const float* __restrict__ target,
    float4_t* __restrict__ sorted, int* __restrict__ binBase, int M) {
  int bs = blockIdx.x;  // b*2 + side
  int b = bs >> 1, side = bs & 1;
  const float* src = (side ? target : pred) + (size_t)b * M * 3;
  float4_t* out = sorted + (size_t)bs * M;
  int* bases = binBase + bs * (NBINS + 1);

  __shared__ int cnt[NBINS];
  __shared__ int scan[NBINS];
  __shared__ int cur[NBINS];
  int t = threadIdx.x;
  for (int i = t; i < NBINS; i += BST) cnt[i] = 0;
  __syncthreads();
  const float invW = (float)NBINS / (XHI - XLO);
  for (int i = t; i < M; i += BST) {
    float x = src[i * 3];
    int bin = (int)((x - XLO) * invW);
    bin = bin < 0 ? 0 : (bin > NBINS - 1 ? NBINS - 1 : bin);
    atomicAdd(&cnt[bin], 1);
  }
  __syncthreads();
  if (t < NBINS) scan[t] = cnt[t];
  __syncthreads();
  for (int off = 1; off < NBINS; off <<= 1) {
    int v = 0;
    if (t < NBINS && t >= off) v = scan[t - off];
    __syncthreads();
    if (t < NBINS) scan[t] += v;
    __syncthreads();
  }
  if (t < NBINS) {
    int excl = scan[t] - cnt[t];
    bases[t] = excl;
    cur[t] = excl;
  }
  if (t == 0) bases[NBINS] = M;
  __syncthreads();
  for (int i = t; i < M; i += BST) {
    float x = src[i * 3], y = src[i * 3 + 1], z = src[i * 3 + 2];
    int bin = (int)((x - XLO) * invW);
    bin = bin < 0 ? 0 : (bin > NBINS - 1 ? NBINS - 1 : bin);
    int pos = atomicAdd(&cur[bin], 1);
    out[pos] = (float4_t){x, y, z, x * x + y * y + z * z};
  }
}

// ---------- pass 2: per-slab window from per-pred NN upper bounds -------
__global__ __launch_bounds__(SLABP) void bound_kernel(
    const float4_t* __restrict__ sorted, const int* __restrict__ binBase,
    int* __restrict__ hdr, int M) {
  int s = blockIdx.x;       // slab id
  int spd = M / SLABP;      // slabs per side (128)
  int bs = s / spd;         // pred side = b*2+dir
  int pblk = s % spd;
  const float4_t* src = sorted + (size_t)bs * M;
  const float4_t* ref = sorted + (size_t)(bs ^ 1) * M;
  const int* rbase = binBase + (bs ^ 1) * (NBINS + 1);

  int t = threadIdx.x;  // one pred per lane (one wave)
  int pbase = pblk * SLABP;
  float4_t p = src[pbase + t];
  float ax = -2.f * p.x, ay = -2.f * p.y, az = -2.f * p.z;

  const float W = (XHI - XLO) / (float)NBINS;
  const float invW = 1.0f / W;
  int bin = (int)((p.x - XLO) * invW);
  bin = bin < 0 ? 0 : (bin > NBINS - 1 ? NBINS - 1 : bin);
  int pos0 = rbase[bin];
  int lo = pos0 - UBN; lo = lo < 0 ? 0 : lo;
  int hi = pos0 + UBN; hi = hi > M ? M : hi;
  float ub = 3.0e38f;  // min over a SUBSET of targets -> valid upper bound
  for (int j = lo; j < hi; ++j) {
    float4_t q = ref[j];
    float d = fmaf(ax, q.x, fmaf(ay, q.y, fmaf(az, q.z, q.w)));
    ub = fminf(ub, d);
  }
  ub += p.w;  // true NN dist^2 <= ub

  float bmax = ub, xmn = p.x, xmx = p.x;
#pragma unroll
  for (int off = 1; off < 64; off <<= 1) {
    bmax = fmaxf(bmax, __shfl_xor(bmax, off, 64));
    xmn = fminf(xmn, __shfl_xor(xmn, off, 64));
    xmx = fmaxf(xmx, __shfl_xor(xmx, off, 64));
  }
  if (t == 0) {
    float r = sqrtf(bmax);
    // -1/+1 bin safety margin: excluded targets provably have
    // (x_p - x_t)^2 > bmax >= NN^2  ->  window min is the exact NN.
    int lb = (int)floorf((xmn - r - XLO) * invW) - 1;
    lb = lb < 0 ? 0 : (lb > NBINS - 1 ? NBINS - 1 : lb);
    int rb = (int)floorf((xmx + r - XLO) * invW) + 1;
    rb = rb < 0 ? 0 : (rb > NBINS - 1 ? NBINS - 1 : rb);
    int Lpos = rbase[lb];
    int Rpos = rbase[rb + 1];
    int nch = (Rpos - Lpos + CHUNK - 1) / CHUNK;  // <= M/CHUNK = 16
    hdr[s * 4 + 0] = Lpos;
    hdr[s * 4 + 1] = Rpos;
    hdr[s * 4 + 2] = nch;
    hdr[s * 4 + 3] = 0;
  }
}

// ---------- pass 3: embarrassingly-parallel chunk scan ------------------
__global__ __launch_bounds__(256, 8) void chunk_kernel(
    const float4_t* __restrict__ sorted, const int* __restrict__ hdr,
    unsigned int* __restrict__ wsmin, int M) {
  int bid = blockIdx.x;
  int s = bid >> 4;       // slab
  int ci = bid & 15;      // chunk index within slab window
  int nch = hdr[s * 4 + 2];
  if (ci >= nch) return;  // inactive block: one L2 read and out
  int Lpos = hdr[s * 4 + 0];
  int Rpos = hdr[s * 4 + 1];
  int spd = M / SLABP;
  int bs = s / spd;
  int pblk = s % spd;
  const float4_t* src = sorted + (size_t)bs * M;
  const float4_t* ref = sorted + (size_t)(bs ^ 1) * M;
  int pbase = pblk * SLABP;
  int start = Lpos + ci * CHUNK;
  int fill = Rpos - start;
  fill = fill > CHUNK ? CHUNK : fill;

  __shared__ float4_t tile[8 * 65];  // rows at banks {0,4,..,28}: no conflict
  int t = threadIdx.x;
#pragma unroll
  for (int k = 0; k < 2; ++k) {  // stage 512 float4, 2 per thread
    int i = t + 256 * k;
    float4_t q = (float4_t){0.f, 0.f, 0.f, 3.0e38f};
    if (i < fill) q = ref[start + i];
    tile[(i >> 6) * 65 + (i & 63)] = q;
  }
  __syncthreads();

  int c = t >> 3;  // cluster 0..31 (8 consecutive lanes)
  int r = t & 7;   // row 0..7
  float4_t v0 = src[pbase + c];
  float4_t v1 = src[pbase + c + 32];
  float ax0 = -2.f * v0.x, ay0 = -2.f * v0.y, az0 = -2.f * v0.z, cm0 = v0.w;
  float ax1 = -2.f * v1.x, ay1 = -2.f * v1.y, az1 = -2.f * v1.z, cm1 = v1.w;
  float mn0 = 3.0e38f, mn1 = 3.0e38f;

  const float4_t* tp = tile + r * 65;  // row r: targets [r*64, r*64+64)
#pragma unroll 2
  for (int j = 0; j < 64; j += 4) {
    float4_t q0 = tp[j + 0];
    float4_t q1 = tp[j + 1];
    float4_t q2 = tp[j + 2];
    float4_t q3 = tp[j + 3];
    float d00 = fmaf(ax0, q0.x, fmaf(ay0, q0.y, fmaf(az0, q0.z, q0.w)));
    float d01 = fmaf(ax0, q1.x, fmaf(ay0, q1.y, fmaf(az0, q1.z, q1.w)));
    float d02 = fmaf(ax0, q2.x, fmaf(ay0, q2.y, fmaf(az0, q2.z, q2.w)));
    float d03 = fmaf(ax0, q3.x, fmaf(ay0, q3.y, fmaf(az0, q3.z, q3.w)));
    mn0 = fminf(fminf(mn0, d00), d01);  // v_min3
    mn0 = fminf(fminf(mn0, d02), d03);
    float d10 = fmaf(ax1, q0.x, fmaf(ay1, q0.y, fmaf(az1, q0.z, q0.w)));
    float d11 = fmaf(ax1, q1.x, fmaf(ay1, q1.y, fmaf(az1, q1.z, q1.w)));
    float d12 = fmaf(ax1, q2.x, fmaf(ay1, q2.y, fmaf(az1, q2.z, q2.w)));
    float d13 = fmaf(ax1, q3.x, fmaf(ay1, q3.y, fmaf(az1, q3.z, q3.w)));
    mn1 = fminf(fminf(mn1, d10), d11);
    mn1 = fminf(fminf(mn1, d12), d13);
  }

  // cluster reduce (xor 1,2,4 toggles r bits only)
  mn0 = fminf(mn0, __shfl_xor(mn0, 1, 64));
  mn0 = fminf(mn0, __shfl_xor(mn0, 2, 64));
  mn0 = fminf(mn0, __shfl_xor(mn0, 4, 64));
  mn1 = fminf(mn1, __shfl_xor(mn1, 1, 64));
  mn1 = fminf(mn1, __shfl_xor(mn1, 2, 64));
  mn1 = fminf(mn1, __shfl_xor(mn1, 4, 64));
  if (r == 0) {
    // positive-float bit order == value order; min(+const) is monotone ->
    // cross-chunk atomicMin selects the exact global min value.
    size_t base = (size_t)bs * M + pbase;
    atomicMin(&wsmin[base + c], __float_as_uint(mn0 + cm0));
    atomicMin(&wsmin[base + c + 32], __float_as_uint(mn1 + cm1));
  }
}

// ---------- pass 4: sum wsmin (bits are positive floats) ----------------
__global__ __launch_bounds__(256) void chamfer_reduce_kernel(
    const float* __restrict__ wsmin, float* __restrict__ out, int npts,
    float scale) {
  int tid = blockIdx.x * blockDim.x + threadIdx.x;
  int stride = gridDim.x * blockDim.x;
  double acc = 0.0;
  for (int p = tid; p < npts; p += stride) acc += (double)wsmin[p];
  for (int off = 32; off > 0; off >>= 1) acc += __shfl_down(acc, off, 64);
  __shared__ double wsum[256 / 64];
  int t = threadIdx.x;
  if ((t & 63) == 0) wsum[t >> 6] = acc;
  __syncthreads();
  if (t == 0) {
    double s = 0.0;
#pragma unroll
    for (int w = 0; w < 256 / 64; ++w) s += wsum[w];
    atomicAdd(out, (float)(s * (double)scale));
  }
}

// =================== fallback: R11 brute force (512KB ws) ===============
__global__ __launch_bounds__(THREADS, 2) void chamfer_brute_kernel(
    const float* __restrict__ pred, const float* __restrict__ target,
    float* __restrict__ wsmin, int M) {
  const int blocksPerDir = M / G;  // 64
  int bid = blockIdx.x;
  int pblk = bid % blocksPerDir;
  int rest = bid / blocksPerDir;
  int ts = rest % TSPLIT;
  int bd = rest / TSPLIT;
  int dir = bd & 1;
  int b = bd >> 1;
  const float* src = (dir ? target : pred) + (size_t)b * M * 3;
  const float* ref = (dir ? pred : target) + (size_t)b * M * 3;

  __shared__ float4_t lds[2 * BUFSZ];

  int t = threadIdx.x;
  int g = t >> 4;
  int l = t & 15;

  float ax[P], ay[P], az[P];
  int pbase = pblk * G;
#pragma unroll
  for (int i = 0; i < P; ++i) {
    int p = pbase + l + 16 * i;
    float x = src[p * 3 + 0], y = src[p * 3 + 1], z = src[p * 3 + 2];
    ax[i] = -2.f * x;
    ay[i] = -2.f * y;
    az[i] = -2.f * z;
  }
  float mn[P];
#pragma unroll
  for (int i = 0; i < P; ++i) mn[i] = 3.0e38f;

  const int spanLen = M / TSPLIT;
  const int tbase = ts * spanLen;
  const int sliceLen = spanLen / 32;   // 128
  const int ntiles = sliceLen / TILE;  // 4

  const int sidx = 2 * t;
  const int ss = sidx >> 5;
  const int sjj = sidx & (TILE - 1);
  const int nb = tbase + ss * sliceLen + sjj;
  float rx0, ry0, rz0, rx1, ry1, rz1;

  {
    int n = nb;
    rx0 = ref[n * 3 + 0]; ry0 = ref[n * 3 + 1]; rz0 = ref[n * 3 + 2];
    rx1 = ref[n * 3 + 3]; ry1 = ref[n * 3 + 4]; rz1 = ref[n * 3 + 5];
    float4_t* dst = lds + ss * LSTRIDE + sjj;
    dst[0] = (float4_t){rx0, ry0, rz0, rx0 * rx0 + ry0 * ry0 + rz0 * rz0};
    dst[1] = (float4_t){rx1, ry1, rz1, rx1 * rx1 + ry1 * ry1 + rz1 * rz1};
  }
  __syncthreads();

  int cur = 0;
  for (int k = 0; k < ntiles; ++k) {
    if (k + 1 < ntiles) {
      int n = nb + (k + 1) * TILE;
      rx0 = ref[n * 3 + 0]; ry0 = ref[n * 3 + 1]; rz0 = ref[n * 3 + 2];
      rx1 = ref[n * 3 + 3]; ry1 = ref[n * 3 + 4]; rz1 = ref[n * 3 + 5];
    }
    const float4_t* tp = lds + cur * BUFSZ + g * LSTRIDE;
#pragma unroll 2
    for (int j = 0; j < TILE; j += 4) {
      float4_t q0 = tp[j + 0];
      float4_t q1 = tp[j + 1];
      float4_t q2 = tp[j + 2];
      float4_t q3 = tp[j + 3];
#pragma unroll
      for (int i = 0; i < P; ++i) {
        float d0 = fmaf(ax[i], q0.x, fmaf(ay[i], q0.y, fmaf(az[i], q0.z, q0.w)));
        float d1 = fmaf(ax[i], q1.x, fmaf(ay[i], q1.y, fmaf(az[i], q1.z, q1.w)));
        float d2 = fmaf(ax[i], q2.x, fmaf(ay[i], q2.y, fmaf(az[i], q2.z, q2.w)));
        float d3 = fmaf(ax[i], q3.x, fmaf(ay[i], q3.y, fmaf(az[i], q3.z, q3.w)));
        mn[i] = fminf(fminf(mn[i], d0), d1);
        mn[i] = fminf(fminf(mn[i], d2), d3);
      }
    }
    if (k + 1 < ntiles) {
      float4_t* dst = lds + (cur ^ 1) * BUFSZ + ss * LSTRIDE + sjj;
      dst[0] = (float4_t){rx0, ry0, rz0, rx0 * rx0 + ry0 * ry0 + rz0 * rz0};
      dst[1] = (float4_t){rx1, ry1, rz1, rx1 * rx1 + ry1 * ry1 + rz1 * rz1};
    }
    __syncthreads();
    cur ^= 1;
  }

  float* lmin = (float*)lds;
#pragma unroll
  for (int i = 0; i < P; ++i) lmin[g * G + (l + 16 * i)] = mn[i];
  __syncthreads();
  if (t < G) {
    float m = 3.0e38f;
#pragma unroll
    for (int s = 0; s < 32; ++s) m = fminf(m, lmin[s * G + t]);
    int p = pbase + t;
    float x = src[p * 3 + 0], y = src[p * 3 + 1], z = src[p * 3 + 2];
    int pid = (b * 2 + dir) * M + p;
    wsmin[(size_t)pid * TSPLIT + ts] = (x * x + y * y + z * z) + m;
  }
}

__global__ __launch_bounds__(256) void chamfer_reduce2_kernel(
    const float* __restrict__ wsmin, float* __restrict__ out, int npts,
    float scale) {
  int tid = blockIdx.x * blockDim.x + threadIdx.x;
  int stride = gridDim.x * blockDim.x;
  double acc = 0.0;
  for (int p = tid; p < npts; p += stride) {
    float2_t v = ((const float2_t*)wsmin)[p];
    acc += (double)fminf(v.x, v.y);
  }
  for (int off = 32; off > 0; off >>= 1) acc += __shfl_down(acc, off, 64);
  __shared__ double wsum[256 / 64];
  int t = threadIdx.x;
  if ((t & 63) == 0) wsum[t >> 6] = acc;
  __syncthreads();
  if (t == 0) {
    double s = 0.0;
#pragma unroll
    for (int w = 0; w < 256 / 64; ++w) s += wsum[w];
    atomicAdd(out, (float)(s * (double)scale));
  }
}

extern "C" void kernel_launch(void* const* d_in, const int* in_sizes, int n_in,
                              void* d_out, int out_size, void* d_ws,
                              size_t ws_size, hipStream_t stream) {
  const float* pred = (const float*)d_in[0];
  const float* target = (const float*)d_in[1];
  float* out = (float*)d_out;
  const int B = 4;
  const int M = in_sizes[0] / (B * 3);  // 8192
  float scale = 1.0f / (float)(B * M);

  hipMemsetAsync(out, 0, sizeof(float), stream);  // d_out is poisoned 0xAA

  // layout: wsmin [B*2*M f32] | sorted [B*2*M float4] | binBase | hdr
  size_t needWsmin = (size_t)B * 2 * M * 4;           // 256 KB
  size_t needSorted = (size_t)B * 2 * M * 16;         // 1 MB
  size_t needBins = (size_t)B * 2 * (NBINS + 1) * 4;  // ~8 KB
  int nslabs = B * 2 * (M / SLABP);                   // 1024
  size_t needHdr = (size_t)nslabs * 4 * 4;            // 16 KB
  size_t need = needWsmin + needSorted + needBins + needHdr;

  if (ws_size >= need) {
    float* wsmin = (float*)d_ws;
    float4_t* sorted = (float4_t*)((char*)d_ws + needWsmin);
    int* binBase = (int*)((char*)sorted + needSorted);
    int* hdr = (int*)((char*)binBase + needBins);

    // init wsmin to 0x7F7F7F7F (~3.39e38 as float; max-ish uint for +floats)
    hipMemsetAsync(wsmin, 0x7F, needWsmin, stream);

    bin_sort_kernel<<<B * 2, BST, 0, stream>>>(pred, target, sorted, binBase,
                                               M);
    bound_kernel<<<nslabs, SLABP, 0, stream>>>(sorted, binBase, hdr, M);
    chunk_kernel<<<nslabs * MAXCH, 256, 0, stream>>>(
        sorted, hdr, (unsigned int*)wsmin, M);
    int npts = B * 2 * M;  // 65536
    chamfer_reduce_kernel<<<64, 256, 0, stream>>>(wsmin, out, npts, scale);
  } else {
    // fallback: R11 brute force, 512 KB ws (known-good at 46.4us dispatch)
    float* wsmin = (float*)d_ws;
    int blocks = B * 2 * (M / G) * TSPLIT;  // 1024
    chamfer_brute_kernel<<<blocks, THREADS, 0, stream>>>(pred, target, wsmin,
                                                         M);
    int npts = B * 2 * M;
    chamfer_reduce2_kernel<<<64, 256, 0, stream>>>(wsmin, out, npts, scale);
  }
}